// Round 2
// baseline (190.562 us; speedup 1.0000x reference)
//
#include <hip/hip_runtime.h>
#include <cstdint>

typedef unsigned long long ull;

#define N_BOX 8192
#define N_WORDS 128   // 8192 / 64
#define CH 512        // chunk size
#define WPC 8         // words per chunk
#define NBLK 16       // k5 blocks = chunks

// ---------------- workspace layout ----------------
// TB (distance>=2 transposed col-blocks): 53760 rows * 64 B = 3,440,640 @ 0
// TC (superdiagonal transposed blocks):   15 * 32 KB        =   491,520 @ 3,440,640
// TD (per-chunk diagonal tables):         16 * 32 KB        =   524,288 @ 3,932,160
// boxes4 : 131072 @ 4,456,448
// scores : 32768  @ 4,587,520
// ctrl   : 4 KB (flags at c*32 ints = 128B apart; vb at int 512) @ 4,620,288
// keptg  : 16 chunks * 16 ull (128B stride)                      @ 4,624,384
#define OFF_TB     0
#define OFF_TC     3440640
#define OFF_TD     3932160
#define OFF_BOXES  4456448
#define OFF_SCORES 4587520
#define OFF_CTRL   4620288
#define OFF_KEPT   4624384

#define CTRL_VB   512    // int index of vb within ctrl
#define KSTRIDE   16     // ull stride per chunk in keptg (128 B padding)

// TB rows for source chunk c' cover j >= CH*(c'+2): 7168-512c' rows (c'=0..13)
__device__ __forceinline__ int rows_before2(int c) {
    return 7424 * c - 256 * c * c;   // sum_{c'<c} (7168 - 512c')
}

__device__ __forceinline__ float box_area(float4 b) {
    return __fmul_rn(__fsub_rn(b.z, b.x), __fsub_rn(b.w, b.y));
}

// exact replica of reference IoU rounding (_rn ops block FMA contraction); symmetric.
__device__ __forceinline__ bool iou_gt_half(float4 a, float aarea, float4 b, float barea) {
    float ix1 = fmaxf(a.x, b.x);
    float iy1 = fmaxf(a.y, b.y);
    float ix2 = fminf(a.z, b.z);
    float iy2 = fminf(a.w, b.w);
    float iw = fmaxf(__fsub_rn(ix2, ix1), 0.0f);
    float ih = fmaxf(__fsub_rn(iy2, iy1), 0.0f);
    float inter = __fmul_rn(iw, ih);
    float uni = __fsub_rn(__fadd_rn(aarea, barea), inter);
    float iou = __fdiv_rn(inter, fmaxf(uni, 1e-9f));
    return iou > 0.5f;
}

// kA: fused max + rank + scatter. 256 blocks x 256 threads; block bx owns
// i in [bx*32, bx*32+32). NO inter-block communication:
//  - every block recomputes the global conf max from LDS (32 KB conf stage;
//    input is L3-resident so the 256x re-read is ~free),
//  - rank[i] = #{j : s_j > s_i || (s_j==s_i && j<i)} counted over ALL 8192 j
//    from LDS (float compare == old 45-bit key order; positive floats),
//  - scatter follows immediately in-block (rank needs no other block).
// This removes two kernel launches and the rank zero-init pass entirely.
// Block 0 additionally computes vb (count s>=0.5) and zeroes the k5 flags.
__global__ __launch_bounds__(256) void kA_rank_scatter(const float* __restrict__ in,
                                                       float4* __restrict__ boxes4,
                                                       float* __restrict__ scores,
                                                       int* __restrict__ ctrl) {
    __shared__ float sc[N_BOX];        // 32 KB: conf, then divided scores in place
    __shared__ float wm[4];
    __shared__ int wv[4];
    int t = threadIdx.x;
    int bx = blockIdx.x;

    for (int k = t; k < N_BOX; k += 256) sc[k] = in[k * 5 + 4];
    __syncthreads();

    // block-local max over all 8192 (conf >= 0 so 0-seeded fmax is safe)
    float m = 0.0f;
    for (int k = t; k < N_BOX; k += 256) m = fmaxf(m, sc[k]);
    for (int off = 32; off; off >>= 1) m = fmaxf(m, __shfl_down(m, off));
    if ((t & 63) == 0) wm[t >> 6] = m;
    __syncthreads();                               // all reads of sc done too
    float maxc = fmaxf(fmaxf(wm[0], wm[1]), fmaxf(wm[2], wm[3]));

    // divide in place (each thread owns its k-slots; no conflict)
    for (int k = t; k < N_BOX; k += 256) sc[k] = __fdiv_rn(sc[k], maxc);
    __syncthreads();

    // rank: 8 threads (seg 0..7) per i, each counting one 1024-j segment.
    // Segment start rotated by seg to spread LDS banks (seg*1024 words are
    // bank-aligned; +seg rotation -> 8 distinct banks per wave).
    int il = t >> 3, seg = t & 7;
    int i = bx * 32 + il;
    float si = sc[i];
    int base = seg * 1024;
    int cnt = 0;
    #pragma unroll 8
    for (int cc = 0; cc < 1024; ++cc) {
        int k = base + ((cc + seg) & 1023);
        float sj = sc[k];
        cnt += (sj > si || (sj == si && k < i)) ? 1 : 0;
    }
    cnt += __shfl_down(cnt, 4, 8);
    cnt += __shfl_down(cnt, 2, 8);
    cnt += __shfl_down(cnt, 1, 8);
    if (seg == 0) {
        int r = cnt;                               // descending-sort position
        float cx = in[i * 5 + 0];
        float cy = in[i * 5 + 1];
        float w  = in[i * 5 + 2];
        float h  = in[i * 5 + 3];
        float4 b;
        b.x = __fsub_rn(cx, __fmul_rn(w, 0.5f));
        b.y = __fsub_rn(cy, __fmul_rn(h, 0.5f));
        b.z = __fadd_rn(cx, __fmul_rn(w, 0.5f));
        b.w = __fadd_rn(cy, __fmul_rn(h, 0.5f));
        boxes4[r] = b;
        scores[r] = si;
    }

    // block 0: vb + zero the k5 chain flags (poisoned workspace)
    if (bx == 0) {
        int cv = 0;
        for (int k = t; k < N_BOX; k += 256) cv += (sc[k] >= 0.5f) ? 1 : 0;
        for (int off = 32; off; off >>= 1) cv += __shfl_down(cv, off);
        if ((t & 63) == 0) wv[t >> 6] = cv;
        if (t < NBLK) ctrl[t * 32] = 0;
        __syncthreads();
        if (t == 0) ctrl[CTRL_VB] = wv[0] + wv[1] + wv[2] + wv[3];
    }
}

// K4: build suppression bit tables.
//  bid <  1680        : TB — source chunk c, target j >= CH*(c+2), 32 j x 8 w tiles
//  1680 <= bid < 1920 : TC — source chunk c (0..14), target chunk c+1; transposed
//                       TC[c][w][jl] = word-w boxes of chunk c suppressing jl
//  bid >= 1920        : TD — diagonal, TD[c][w][jl], pre-masked to suppressors < jl
__global__ __launch_bounds__(256) void k4_build(const float4* __restrict__ boxes4,
                                                const float* __restrict__ scores,
                                                ull* __restrict__ TB,
                                                ull* __restrict__ TC,
                                                ull* __restrict__ TD) {
    __shared__ float4 sb[CH];
    __shared__ float sa[CH];
    int bid = blockIdx.x;
    int t = threadIdx.x;
    int c;
    int mode;   // 0=TB, 1=TC, 2=TD
    int j0;     // TB: global j tile start; TC/TD: local jl tile start
    if (bid >= 1920) {
        mode = 2;
        int d = bid - 1920;
        c = d >> 4;
        j0 = (d & 15) * 32;
    } else if (bid >= 1680) {
        mode = 1;
        int d = bid - 1680;
        c = d >> 4;          // 0..14
        j0 = (d & 15) * 32;
    } else {
        mode = 0;
        c = 0;
        int rem = bid;
        while (rem >= 224 - 16 * c) { rem -= 224 - 16 * c; ++c; }
        j0 = CH * (c + 2) + rem * 32;
    }
    if (scores[c * CH] < 0.5f) return;               // source chunk never a suppressor
    if (mode == 0 && scores[j0] < 0.5f) return;      // j-tile never alive (desc scores)

    for (int i = t; i < CH; i += 256) {
        float4 b = boxes4[c * CH + i];
        sb[i] = b;
        sa[i] = box_area(b);
    }
    __syncthreads();

    int w = t & 7;
    int r = t >> 3;          // 0..31 local row
    if (mode == 2) {
        int jl = j0 + r;
        float4 me = sb[jl];
        float ma = sa[jl];
        int wj = jl >> 6;
        int lim = (w < wj) ? 64 : ((w == wj) ? (jl & 63) : 0);
        ull bits = 0;
        for (int k = 0; k < lim; ++k)
            if (iou_gt_half(sb[w * 64 + k], sa[w * 64 + k], me, ma)) bits |= 1ull << k;
        TD[c * 4096 + w * 512 + jl] = bits;
    } else if (mode == 1) {
        int jl = j0 + r;
        int j = CH * (c + 1) + jl;
        float4 me = boxes4[j];
        float ma = box_area(me);
        ull bits = 0;
        for (int k = 0; k < 64; ++k)
            if (iou_gt_half(sb[w * 64 + k], sa[w * 64 + k], me, ma)) bits |= 1ull << k;
        TC[c * 4096 + w * 512 + jl] = bits;
    } else {
        int j = j0 + r;
        float4 me = boxes4[j];
        float ma = box_area(me);
        ull bits = 0;
        for (int k = 0; k < 64; ++k)
            if (iou_gt_half(sb[w * 64 + k], sa[w * 64 + k], me, ma)) bits |= 1ull << k;
        TB[(size_t)(rows_before2(c) + (j - CH * (c + 2))) * WPC + w] = bits;
    }
}

// K5: pipelined multi-block greedy NMS, block c owns chunk c.
// Handoff redesign vs last round (the chain cost was dominated by atomic-RMW
// polling: every atomicAdd(&flag,0) takes EXCLUSIVE ownership of the line,
// and 15 blocks hammering one 128B line ping-pongs it across 8 XCDs):
//  - flags padded to 128 B each (ctrl[c*32]); kept words padded to 128 B/chunk
//  - consumers spin with read-only __hip_atomic_load(ACQUIRE, AGENT) — no
//    ownership transfer, concurrent pollers share the line
//  - producer publishes from lane 0 only: 8 relaxed agent stores (alive[] is
//    wave-uniform after ballots) + 1 RELEASE store of the flag (orders them)
//  - consumer lane 0 acquires the flag, reads the 8 kept words (relaxed,
//    ordered after its acquire), stores to LDS; __syncthreads publishes
//    in-block.
__global__ __launch_bounds__(1024) void k5_nms(const float4* __restrict__ boxes4,
                                               const float* __restrict__ scores,
                                               const ull* __restrict__ TBg,
                                               const ull* __restrict__ TCg,
                                               const ull* __restrict__ TDg,
                                               ull* __restrict__ keptg,
                                               int* __restrict__ ctrl,
                                               float* __restrict__ out) {
    __shared__ ull TDs[CH * WPC];      // 32 KB: TD[c]
    __shared__ ull TCs[CH * WPC];      // 32 KB: TC[c-1]
    __shared__ ull kwsh[WPC];
    __shared__ unsigned amask[16];     // 512 alive bits for own chunk
    int c = blockIdx.x;
    int t = threadIdx.x;
    int lane = t & 63;
    int wave = t >> 6;
    int vb = ctrl[CTRL_VB];
    int nchv = (vb + CH - 1) / CH;

    if (c < nchv) {
        // ---- stage TD[c] (and TC[c-1]) into LDS; init alive mask ----
        {
            const ulonglong2* src = (const ulonglong2*)(TDg + (size_t)c * CH * WPC);
            ulonglong2* dst = (ulonglong2*)TDs;
            #pragma unroll
            for (int i2 = t; i2 < CH * WPC / 2; i2 += 1024) dst[i2] = src[i2];
        }
        if (c > 0) {
            const ulonglong2* src = (const ulonglong2*)(TCg + (size_t)(c - 1) * CH * WPC);
            ulonglong2* dst = (ulonglong2*)TCs;
            #pragma unroll
            for (int i2 = t; i2 < CH * WPC / 2; i2 += 1024) dst[i2] = src[i2];
        }
        if (t < 16) {
            int n = vb - (c * 16 + t) * 32;
            amask[t] = (n >= 32) ? 0xffffffffu : ((n <= 0) ? 0u : ((1u << n) - 1u));
        }
        __syncthreads();

        // ---- TB applies: kept[cp] -> own chunk, cp = 0..c-2 ----
        // Flags publish in chunk order, so early iterations return instantly
        // and the cp=c-2 apply overlaps block c-1's TC+scan.
        for (int cp = 0; cp + 2 <= c; ++cp) {
            if (wave == 0 && lane == 0) {
                while (__hip_atomic_load(&ctrl[cp * 32], __ATOMIC_ACQUIRE,
                                         __HIP_MEMORY_SCOPE_AGENT) == 0) {}
                #pragma unroll
                for (int w = 0; w < WPC; ++w)
                    kwsh[w] = __hip_atomic_load(&keptg[cp * KSTRIDE + w],
                                                __ATOMIC_RELAXED,
                                                __HIP_MEMORY_SCOPE_AGENT);
            }
            __syncthreads();
            ull anyk = kwsh[0] | kwsh[1] | kwsh[2] | kwsh[3] |
                       kwsh[4] | kwsh[5] | kwsh[6] | kwsh[7];
            if (anyk && t < CH) {
                if ((amask[t >> 5] >> (t & 31)) & 1u) {
                    const ull* row = TBg +
                        (size_t)(rows_before2(cp) + (c * CH + t - CH * (cp + 2))) * WPC;
                    ull a = 0;
                    #pragma unroll
                    for (int q = 0; q < WPC; ++q) a |= row[q] & kwsh[q];
                    if (a) atomicAnd(&amask[t >> 5], ~(1u << (t & 31)));
                }
            }
            __syncthreads();
        }

        // ---- TC apply: kept[c-1] -> own chunk (wave v handles target word v) ----
        if (c > 0) {
            if (wave == 0 && lane == 0) {
                while (__hip_atomic_load(&ctrl[(c - 1) * 32], __ATOMIC_ACQUIRE,
                                         __HIP_MEMORY_SCOPE_AGENT) == 0) {}
                #pragma unroll
                for (int w = 0; w < WPC; ++w)
                    kwsh[w] = __hip_atomic_load(&keptg[(c - 1) * KSTRIDE + w],
                                                __ATOMIC_RELAXED,
                                                __HIP_MEMORY_SCOPE_AGENT);
            }
            __syncthreads();
            if (wave < WPC) {
                bool dead = false;
                #pragma unroll
                for (int w = 0; w < WPC; ++w) {
                    ull kw = kwsh[w];
                    if (kw) dead |= (TCs[w * 512 + wave * 64 + lane] & kw) != 0ull;
                }
                ull d = __ballot(dead);
                if (lane == 0 && d) {
                    amask[2 * wave]     &= ~(unsigned)d;
                    amask[2 * wave + 1] &= ~(unsigned)(d >> 32);
                }
            }
            __syncthreads();
        }

        // ---- scan own chunk (wave 0): TD fixpoint, then publish ----
        if (wave == 0) {
            ull alive[WPC];
            #pragma unroll
            for (int w = 0; w < WPC; ++w)
                alive[w] = (ull)amask[2 * w] | ((ull)amask[2 * w + 1] << 32);
            const ull* T = TDs;
            #pragma unroll
            for (int w = 0; w < WPC; ++w) {
                ull word = alive[w];
                if (!word) continue;
                ull Tc[WPC];
                #pragma unroll
                for (int j = 0; j < WPC; ++j)
                    if (j >= w) Tc[j] = T[w * 512 + j * 64 + lane];
                ull td = Tc[w];
                ull a2 = word, kept = 0;
                while (a2 & ~kept) {
                    bool al = (a2 >> lane) & 1;
                    bool kp = (kept >> lane) & 1;
                    ull nk = __ballot(al && !kp && ((td & a2) == 0));
                    ull nd = __ballot(al && !kp && ((td & kept) != 0));
                    kept |= nk;
                    a2 &= ~nd;
                }
                alive[w] = kept;
                #pragma unroll
                for (int j = 0; j < WPC; ++j) {
                    if (j <= w) continue;
                    if (!alive[j]) continue;
                    alive[j] &= ~__ballot((Tc[j] & kept) != 0);
                }
            }
            if (lane == 0) {
                #pragma unroll
                for (int w = 0; w < WPC; ++w) {
                    // alive[] is wave-uniform (ballot results): lane 0 owns publish
                    __hip_atomic_store(&keptg[c * KSTRIDE + w], alive[w],
                                       __ATOMIC_RELAXED, __HIP_MEMORY_SCOPE_AGENT);
                    amask[2 * w]     = (unsigned)alive[w];
                    amask[2 * w + 1] = (unsigned)(alive[w] >> 32);
                }
                __hip_atomic_store(&ctrl[c * 32], 1,
                                   __ATOMIC_RELEASE, __HIP_MEMORY_SCOPE_AGENT);
            }
        }
        __syncthreads();
    } else {
        if (t < 16) amask[t] = 0u;
        __syncthreads();
    }

    // ---- epilogue: write own 512 output rows ----
    if (t < CH) {
        int j = c * CH + t;
        bool kept = (amask[t >> 5] >> (t & 31)) & 1u;
        float4 b = boxes4[j];
        float s = scores[j];
        out[j * 5 + 0] = kept ? b.x : 0.0f;
        out[j * 5 + 1] = kept ? b.y : 0.0f;
        out[j * 5 + 2] = kept ? b.z : 0.0f;
        out[j * 5 + 3] = kept ? b.w : 0.0f;
        out[j * 5 + 4] = kept ? s   : 0.0f;
    }
}

extern "C" void kernel_launch(void* const* d_in, const int* in_sizes, int n_in,
                              void* d_out, int out_size, void* d_ws, size_t ws_size,
                              hipStream_t stream) {
    const float* in = (const float*)d_in[0];
    char* ws = (char*)d_ws;
    ull* TB        = (ull*)(ws + OFF_TB);
    ull* TC        = (ull*)(ws + OFF_TC);
    ull* TD        = (ull*)(ws + OFF_TD);
    float4* boxes4 = (float4*)(ws + OFF_BOXES);
    float* scores  = (float*)(ws + OFF_SCORES);
    int* ctrl      = (int*)(ws + OFF_CTRL);
    ull* keptg     = (ull*)(ws + OFF_KEPT);
    float* out     = (float*)d_out;

    kA_rank_scatter<<<256, 256, 0, stream>>>(in, boxes4, scores, ctrl);
    k4_build<<<2176, 256, 0, stream>>>(boxes4, scores, TB, TC, TD);
    k5_nms<<<NBLK, 1024, 0, stream>>>(boxes4, scores, TB, TC, TD, keptg, ctrl, out);
}

// Round 3
// 126.499 us; speedup vs baseline: 1.5064x; 1.5064x over previous
//
#include <hip/hip_runtime.h>
#include <cstdint>

typedef unsigned long long ull;

#define N_BOX 8192
#define N_WORDS 128   // 8192 / 64
#define CH 512        // chunk size
#define WPC 8         // words per chunk
#define NBLK 16       // k5 blocks = chunks

// ---------------- workspace layout ----------------
// TB (distance>=2 transposed col-blocks): 53760 rows * 64 B = 3,440,640 @ 0
// TC (superdiagonal transposed blocks):   15 * 32 KB        =   491,520 @ 3,440,640
// TD (per-chunk diagonal tables):         16 * 32 KB        =   524,288 @ 3,932,160
// boxes4 : 131072 @ 4,456,448
// scores : 32768  @ 4,587,520
// ctrl   : 4 KB (flags at c*32 ints = 128B apart; vb at int 512) @ 4,620,288
// keptg  : 16 chunks * 16 ull (128B stride)                      @ 4,624,384
#define OFF_TB     0
#define OFF_TC     3440640
#define OFF_TD     3932160
#define OFF_BOXES  4456448
#define OFF_SCORES 4587520
#define OFF_CTRL   4620288
#define OFF_KEPT   4624384

#define CTRL_VB   512    // int index of vb within ctrl
#define KSTRIDE   16     // ull stride per chunk in keptg (128 B padding)

// TB rows for source chunk c' cover j >= CH*(c'+2): 7168-512c' rows (c'=0..13)
__device__ __forceinline__ int rows_before2(int c) {
    return 7424 * c - 256 * c * c;   // sum_{c'<c} (7168 - 512c')
}

__device__ __forceinline__ ull make_key(float s, int idx) {
    // positive floats: bit pattern is order-preserving. Reversed index in the
    // low 13 bits reproduces stable argsort(-conf): equal conf -> lower index first.
    return (((ull)__float_as_uint(s)) << 13) | (ull)(8191 - idx);
}

__device__ __forceinline__ float box_area(float4 b) {
    return __fmul_rn(__fsub_rn(b.z, b.x), __fsub_rn(b.w, b.y));
}

// exact replica of reference IoU rounding (_rn ops block FMA contraction); symmetric.
__device__ __forceinline__ bool iou_gt_half(float4 a, float aarea, float4 b, float barea) {
    float ix1 = fmaxf(a.x, b.x);
    float iy1 = fmaxf(a.y, b.y);
    float ix2 = fminf(a.z, b.z);
    float iy2 = fminf(a.w, b.w);
    float iw = fmaxf(__fsub_rn(ix2, ix1), 0.0f);
    float ih = fmaxf(__fsub_rn(iy2, iy1), 0.0f);
    float inter = __fmul_rn(iw, ih);
    float uni = __fsub_rn(__fadd_rn(aarea, barea), inter);
    float iou = __fdiv_rn(inter, fmaxf(uni, 1e-9f));
    return iou > 0.5f;
}

// k123: fused max + rank + scatter (one launch replaces k1/k2/k3).
// 256 blocks x 256 threads; block bx owns i in [bx*32, bx*32+32).
//  - each block recomputes the global conf max itself (fmax is exact: every
//    block derives the bit-identical max -> bit-identical keys),
//  - ALL 8192 keys staged in 64 KB LDS; rank via old-k2's PROVEN loop shape:
//    u64 key compare with LDS address = base + compile-time immediate
//    (kb[cc*8]); round 2 showed per-lane DYNAMIC LDS addressing serializes
//    on ds_read latency (87 us) — this shape pipelines (old k2 was fast).
//    8 threads per i; seg s scans the strided subset {8*cc+s}; bank =
//    (2*seg + 16*cc) % 32 -> 8 distinct banks, conflict-free.
//  - scatter immediately in-block (rank is complete locally; no atomics,
//    no rank array, no zero-init pass).
// Block 0 additionally zeroes the k5 chain flags and publishes vb.
__global__ __launch_bounds__(256) void k123_rank_scatter(const float* __restrict__ in,
                                                         float4* __restrict__ boxes4,
                                                         float* __restrict__ scores,
                                                         int* __restrict__ ctrl) {
    __shared__ ull keys[N_BOX];        // 64 KB
    __shared__ float wm[4];
    __shared__ int wv[4];
    int t = threadIdx.x;
    int bx = blockIdx.x;

    // ---- stage confs into regs; block-local max (== global max, exact) ----
    float cf[32];
    float m = 0.0f;                    // conf >= 0 so 0-seed is safe
    #pragma unroll
    for (int r = 0; r < 32; ++r) {
        cf[r] = in[(r * 256 + t) * 5 + 4];
        m = fmaxf(m, cf[r]);
    }
    for (int off = 32; off; off >>= 1) m = fmaxf(m, __shfl_down(m, off));
    if ((t & 63) == 0) wm[t >> 6] = m;
    __syncthreads();
    float maxc = fmaxf(fmaxf(wm[0], wm[1]), fmaxf(wm[2], wm[3]));

    // ---- build all 8192 keys ----
    #pragma unroll
    for (int r = 0; r < 32; ++r) {
        int k = r * 256 + t;
        keys[k] = make_key(__fdiv_rn(cf[r], maxc), k);
    }
    __syncthreads();

    // ---- rank: 8 threads per i, seg scans {8*cc+seg}, immediate offsets ----
    int il = t >> 3, seg = t & 7;
    int i = bx * 32 + il;
    ull ki = keys[i];
    const ull* kb = keys + seg;
    int cnt = 0;
    #pragma unroll 8
    for (int cc = 0; cc < 1024; ++cc)
        cnt += (kb[cc * 8] > ki) ? 1 : 0;
    cnt += __shfl_down(cnt, 4, 8);
    cnt += __shfl_down(cnt, 2, 8);
    cnt += __shfl_down(cnt, 1, 8);

    // ---- scatter (seg 0 owns i) ----
    if (seg == 0) {
        int r = cnt;                               // descending-sort position
        float cx = in[i * 5 + 0];
        float cy = in[i * 5 + 1];
        float w  = in[i * 5 + 2];
        float h  = in[i * 5 + 3];
        float s  = __fdiv_rn(in[i * 5 + 4], maxc);
        float4 b;
        b.x = __fsub_rn(cx, __fmul_rn(w, 0.5f));
        b.y = __fsub_rn(cy, __fmul_rn(h, 0.5f));
        b.z = __fadd_rn(cx, __fmul_rn(w, 0.5f));
        b.w = __fadd_rn(cy, __fmul_rn(h, 0.5f));
        boxes4[r] = b;
        scores[r] = s;
    }

    // ---- block 0: vb (count s>=0.5 via key threshold) + zero k5 flags ----
    if (bx == 0) {
        const ull kthr = ((ull)0x3F000000u) << 13;   // s >= 0.5 boundary
        int cv = 0;
        for (int k = t; k < N_BOX; k += 256) cv += (keys[k] >= kthr) ? 1 : 0;
        for (int off = 32; off; off >>= 1) cv += __shfl_down(cv, off);
        if ((t & 63) == 0) wv[t >> 6] = cv;
        if (t < NBLK) ctrl[t * 32] = 0;
        __syncthreads();
        if (t == 0) ctrl[CTRL_VB] = wv[0] + wv[1] + wv[2] + wv[3];
    }
}

// K4: build suppression bit tables.
//  bid <  1680        : TB — source chunk c, target j >= CH*(c+2), 32 j x 8 w tiles
//  1680 <= bid < 1920 : TC — source chunk c (0..14), target chunk c+1; transposed
//                       TC[c][w][jl] = word-w boxes of chunk c suppressing jl
//  bid >= 1920        : TD — diagonal, TD[c][w][jl], pre-masked to suppressors < jl
__global__ __launch_bounds__(256) void k4_build(const float4* __restrict__ boxes4,
                                                const float* __restrict__ scores,
                                                ull* __restrict__ TB,
                                                ull* __restrict__ TC,
                                                ull* __restrict__ TD) {
    __shared__ float4 sb[CH];
    __shared__ float sa[CH];
    int bid = blockIdx.x;
    int t = threadIdx.x;
    int c;
    int mode;   // 0=TB, 1=TC, 2=TD
    int j0;     // TB: global j tile start; TC/TD: local jl tile start
    if (bid >= 1920) {
        mode = 2;
        int d = bid - 1920;
        c = d >> 4;
        j0 = (d & 15) * 32;
    } else if (bid >= 1680) {
        mode = 1;
        int d = bid - 1680;
        c = d >> 4;          // 0..14
        j0 = (d & 15) * 32;
    } else {
        mode = 0;
        c = 0;
        int rem = bid;
        while (rem >= 224 - 16 * c) { rem -= 224 - 16 * c; ++c; }
        j0 = CH * (c + 2) + rem * 32;
    }
    if (scores[c * CH] < 0.5f) return;               // source chunk never a suppressor
    if (mode == 0 && scores[j0] < 0.5f) return;      // j-tile never alive (desc scores)

    for (int i = t; i < CH; i += 256) {
        float4 b = boxes4[c * CH + i];
        sb[i] = b;
        sa[i] = box_area(b);
    }
    __syncthreads();

    int w = t & 7;
    int r = t >> 3;          // 0..31 local row
    if (mode == 2) {
        int jl = j0 + r;
        float4 me = sb[jl];
        float ma = sa[jl];
        int wj = jl >> 6;
        int lim = (w < wj) ? 64 : ((w == wj) ? (jl & 63) : 0);
        ull bits = 0;
        for (int k = 0; k < lim; ++k)
            if (iou_gt_half(sb[w * 64 + k], sa[w * 64 + k], me, ma)) bits |= 1ull << k;
        TD[c * 4096 + w * 512 + jl] = bits;
    } else if (mode == 1) {
        int jl = j0 + r;
        int j = CH * (c + 1) + jl;
        float4 me = boxes4[j];
        float ma = box_area(me);
        ull bits = 0;
        for (int k = 0; k < 64; ++k)
            if (iou_gt_half(sb[w * 64 + k], sa[w * 64 + k], me, ma)) bits |= 1ull << k;
        TC[c * 4096 + w * 512 + jl] = bits;
    } else {
        int j = j0 + r;
        float4 me = boxes4[j];
        float ma = box_area(me);
        ull bits = 0;
        for (int k = 0; k < 64; ++k)
            if (iou_gt_half(sb[w * 64 + k], sa[w * 64 + k], me, ma)) bits |= 1ull << k;
        TB[(size_t)(rows_before2(c) + (j - CH * (c + 2))) * WPC + w] = bits;
    }
}

// K5: pipelined multi-block greedy NMS, block c owns chunk c (round-2 version,
// verified passing). Handoff: flags padded to 128 B; consumers spin with
// read-only __hip_atomic_load(ACQUIRE, AGENT) (no line ownership transfer);
// producer publishes kept words relaxed + one RELEASE flag store from lane 0.
__global__ __launch_bounds__(1024) void k5_nms(const float4* __restrict__ boxes4,
                                               const float* __restrict__ scores,
                                               const ull* __restrict__ TBg,
                                               const ull* __restrict__ TCg,
                                               const ull* __restrict__ TDg,
                                               ull* __restrict__ keptg,
                                               int* __restrict__ ctrl,
                                               float* __restrict__ out) {
    __shared__ ull TDs[CH * WPC];      // 32 KB: TD[c]
    __shared__ ull TCs[CH * WPC];      // 32 KB: TC[c-1]
    __shared__ ull kwsh[WPC];
    __shared__ unsigned amask[16];     // 512 alive bits for own chunk
    int c = blockIdx.x;
    int t = threadIdx.x;
    int lane = t & 63;
    int wave = t >> 6;
    int vb = ctrl[CTRL_VB];
    int nchv = (vb + CH - 1) / CH;

    if (c < nchv) {
        // ---- stage TD[c] (and TC[c-1]) into LDS; init alive mask ----
        {
            const ulonglong2* src = (const ulonglong2*)(TDg + (size_t)c * CH * WPC);
            ulonglong2* dst = (ulonglong2*)TDs;
            #pragma unroll
            for (int i2 = t; i2 < CH * WPC / 2; i2 += 1024) dst[i2] = src[i2];
        }
        if (c > 0) {
            const ulonglong2* src = (const ulonglong2*)(TCg + (size_t)(c - 1) * CH * WPC);
            ulonglong2* dst = (ulonglong2*)TCs;
            #pragma unroll
            for (int i2 = t; i2 < CH * WPC / 2; i2 += 1024) dst[i2] = src[i2];
        }
        if (t < 16) {
            int n = vb - (c * 16 + t) * 32;
            amask[t] = (n >= 32) ? 0xffffffffu : ((n <= 0) ? 0u : ((1u << n) - 1u));
        }
        __syncthreads();

        // ---- TB applies: kept[cp] -> own chunk, cp = 0..c-2 ----
        // Flags publish in chunk order, so early iterations return instantly
        // and the cp=c-2 apply overlaps block c-1's TC+scan.
        for (int cp = 0; cp + 2 <= c; ++cp) {
            if (wave == 0 && lane == 0) {
                while (__hip_atomic_load(&ctrl[cp * 32], __ATOMIC_ACQUIRE,
                                         __HIP_MEMORY_SCOPE_AGENT) == 0) {}
                #pragma unroll
                for (int w = 0; w < WPC; ++w)
                    kwsh[w] = __hip_atomic_load(&keptg[cp * KSTRIDE + w],
                                                __ATOMIC_RELAXED,
                                                __HIP_MEMORY_SCOPE_AGENT);
            }
            __syncthreads();
            ull anyk = kwsh[0] | kwsh[1] | kwsh[2] | kwsh[3] |
                       kwsh[4] | kwsh[5] | kwsh[6] | kwsh[7];
            if (anyk && t < CH) {
                if ((amask[t >> 5] >> (t & 31)) & 1u) {
                    const ull* row = TBg +
                        (size_t)(rows_before2(cp) + (c * CH + t - CH * (cp + 2))) * WPC;
                    ull a = 0;
                    #pragma unroll
                    for (int q = 0; q < WPC; ++q) a |= row[q] & kwsh[q];
                    if (a) atomicAnd(&amask[t >> 5], ~(1u << (t & 31)));
                }
            }
            __syncthreads();
        }

        // ---- TC apply: kept[c-1] -> own chunk (wave v handles target word v) ----
        if (c > 0) {
            if (wave == 0 && lane == 0) {
                while (__hip_atomic_load(&ctrl[(c - 1) * 32], __ATOMIC_ACQUIRE,
                                         __HIP_MEMORY_SCOPE_AGENT) == 0) {}
                #pragma unroll
                for (int w = 0; w < WPC; ++w)
                    kwsh[w] = __hip_atomic_load(&keptg[(c - 1) * KSTRIDE + w],
                                                __ATOMIC_RELAXED,
                                                __HIP_MEMORY_SCOPE_AGENT);
            }
            __syncthreads();
            if (wave < WPC) {
                bool dead = false;
                #pragma unroll
                for (int w = 0; w < WPC; ++w) {
                    ull kw = kwsh[w];
                    if (kw) dead |= (TCs[w * 512 + wave * 64 + lane] & kw) != 0ull;
                }
                ull d = __ballot(dead);
                if (lane == 0 && d) {
                    amask[2 * wave]     &= ~(unsigned)d;
                    amask[2 * wave + 1] &= ~(unsigned)(d >> 32);
                }
            }
            __syncthreads();
        }

        // ---- scan own chunk (wave 0): TD fixpoint, then publish ----
        if (wave == 0) {
            ull alive[WPC];
            #pragma unroll
            for (int w = 0; w < WPC; ++w)
                alive[w] = (ull)amask[2 * w] | ((ull)amask[2 * w + 1] << 32);
            const ull* T = TDs;
            #pragma unroll
            for (int w = 0; w < WPC; ++w) {
                ull word = alive[w];
                if (!word) continue;
                ull Tc[WPC];
                #pragma unroll
                for (int j = 0; j < WPC; ++j)
                    if (j >= w) Tc[j] = T[w * 512 + j * 64 + lane];
                ull td = Tc[w];
                ull a2 = word, kept = 0;
                while (a2 & ~kept) {
                    bool al = (a2 >> lane) & 1;
                    bool kp = (kept >> lane) & 1;
                    ull nk = __ballot(al && !kp && ((td & a2) == 0));
                    ull nd = __ballot(al && !kp && ((td & kept) != 0));
                    kept |= nk;
                    a2 &= ~nd;
                }
                alive[w] = kept;
                #pragma unroll
                for (int j = 0; j < WPC; ++j) {
                    if (j <= w) continue;
                    if (!alive[j]) continue;
                    alive[j] &= ~__ballot((Tc[j] & kept) != 0);
                }
            }
            if (lane == 0) {
                #pragma unroll
                for (int w = 0; w < WPC; ++w) {
                    // alive[] is wave-uniform (ballot results): lane 0 owns publish
                    __hip_atomic_store(&keptg[c * KSTRIDE + w], alive[w],
                                       __ATOMIC_RELAXED, __HIP_MEMORY_SCOPE_AGENT);
                    amask[2 * w]     = (unsigned)alive[w];
                    amask[2 * w + 1] = (unsigned)(alive[w] >> 32);
                }
                __hip_atomic_store(&ctrl[c * 32], 1,
                                   __ATOMIC_RELEASE, __HIP_MEMORY_SCOPE_AGENT);
            }
        }
        __syncthreads();
    } else {
        if (t < 16) amask[t] = 0u;
        __syncthreads();
    }

    // ---- epilogue: write own 512 output rows ----
    if (t < CH) {
        int j = c * CH + t;
        bool kept = (amask[t >> 5] >> (t & 31)) & 1u;
        float4 b = boxes4[j];
        float s = scores[j];
        out[j * 5 + 0] = kept ? b.x : 0.0f;
        out[j * 5 + 1] = kept ? b.y : 0.0f;
        out[j * 5 + 2] = kept ? b.z : 0.0f;
        out[j * 5 + 3] = kept ? b.w : 0.0f;
        out[j * 5 + 4] = kept ? s   : 0.0f;
    }
}

extern "C" void kernel_launch(void* const* d_in, const int* in_sizes, int n_in,
                              void* d_out, int out_size, void* d_ws, size_t ws_size,
                              hipStream_t stream) {
    const float* in = (const float*)d_in[0];
    char* ws = (char*)d_ws;
    ull* TB        = (ull*)(ws + OFF_TB);
    ull* TC        = (ull*)(ws + OFF_TC);
    ull* TD        = (ull*)(ws + OFF_TD);
    float4* boxes4 = (float4*)(ws + OFF_BOXES);
    float* scores  = (float*)(ws + OFF_SCORES);
    int* ctrl      = (int*)(ws + OFF_CTRL);
    ull* keptg     = (ull*)(ws + OFF_KEPT);
    float* out     = (float*)d_out;

    k123_rank_scatter<<<256, 256, 0, stream>>>(in, boxes4, scores, ctrl);
    k4_build<<<2176, 256, 0, stream>>>(boxes4, scores, TB, TC, TD);
    k5_nms<<<NBLK, 1024, 0, stream>>>(boxes4, scores, TB, TC, TD, keptg, ctrl, out);
}